// Round 3
// baseline (1446.104 us; speedup 1.0000x reference)
//
#include <hip/hip_runtime.h>
#include <hip/hip_bf16.h>

// GraphProp: hv'[n] = GRU(a[n], hv[n]) with a = segment_sum over incoming edges
// of Linear(concat(h_dst, h_src)). Linearity trick:
//   a[n] = Wl @ (deg[n]*h[n]) + Wr @ S[n] + deg[n]*b,  S[n] = sum_{e:dst=n} h[src]
// => no [E,2H]x[2H,2H] edge GEMM; just CSR segment-sum + node GEMMs (42.6 GF total).
//
// R2 post-mortem: NaN with bf16-input reads; code audit clean => inputs are most
// likely fp32 (per harness docstring). This round: RUNTIME dtype detection
// (flags[1]: floats fp32 vs bf16; flags[0]: edge_src int64 vs int32) so either
// world works. Control buffers first in ws carve; ~124 MB total.

#define NN 50000
#define NE 1600000
#define HH 128
#define TT 2

__device__ __forceinline__ float bf2f(unsigned short u) {
    union { unsigned int i; float f; } c;
    c.i = ((unsigned int)u) << 16;
    return c.f;
}

// ---------- dtype detectors ----------
// flags[0] = edge_src is int64; flags[1] = float inputs are fp32
__global__ void detect_kernel(const unsigned short* __restrict__ hv_u16,
                              const int* __restrict__ src, int* __restrict__ flags) {
    int i = threadIdx.x;  // 64 threads
    // Sample even u16 slots of hv. True bf16 N(0,1): exponent ~[0x66,0x82].
    // fp32 low-halves: uniform random bits -> wild exponents.
    int garbage = 0;
    for (int k = 0; k < 4; k++) {
        unsigned short u = hv_u16[2 * (i * 4 + k)];
        int e = (u >> 7) & 0xFF;
        if (e >= 0x90 || (e <= 0x60 && (u & 0x7FFF) != 0)) garbage++;
    }
    unsigned long long gb = __ballot(garbage > 0);
    int odd = src[2 * i + 1];
    unsigned long long bal = __ballot(odd == 0);
    if (i == 0) {
        flags[1] = (__popcll(gb) >= 8) ? 1 : 0;
        flags[0] = (bal == 0xFFFFFFFFFFFFFFFFull) ? 1 : 0;
    }
}

// ---------- flag-aware float load: fp32 or bf16 -> fp32 ----------
__global__ void conv_kernel(const void* __restrict__ in, float* __restrict__ out,
                            int n, const int* __restrict__ flags) {
    int i = blockIdx.x * blockDim.x + threadIdx.x;
    if (i >= n) return;
    out[i] = flags[1] ? ((const float*)in)[i]
                      : bf2f(((const unsigned short*)in)[i]);
}

// ---------- degree histogram ----------
__global__ void hist_kernel(const int* __restrict__ dst, int* __restrict__ deg, int e) {
    int i = blockIdx.x * blockDim.x + threadIdx.x;
    if (i < e) atomicAdd(&deg[dst[i]], 1);
}

// ---------- single-block exclusive scan over deg -> row offsets ----------
__global__ void scan_kernel(const int* __restrict__ deg, int* __restrict__ row,
                            int* __restrict__ fill, int n) {
    __shared__ int sh[1024];
    __shared__ int s_running;
    if (threadIdx.x == 0) s_running = 0;
    __syncthreads();
    int nch = (n + 1024) / 1024;
    for (int c = 0; c < nch; c++) {
        int idx = c * 1024 + threadIdx.x;
        int v = (idx < n) ? deg[idx] : 0;
        sh[threadIdx.x] = v;
        __syncthreads();
        for (int off = 1; off < 1024; off <<= 1) {
            int t = (threadIdx.x >= off) ? sh[threadIdx.x - off] : 0;
            __syncthreads();
            sh[threadIdx.x] += t;
            __syncthreads();
        }
        int incl = sh[threadIdx.x];
        int excl = incl - v;
        int base = s_running;
        if (idx <= n) row[idx] = base + excl;
        if (idx < n) fill[idx] = base + excl;
        __syncthreads();
        if (threadIdx.x == 1023) s_running = base + incl;
        __syncthreads();
    }
}

// ---------- scatter edge sources into CSR buckets ----------
__global__ void scatter_kernel(const int* __restrict__ src, const int* __restrict__ dst,
                               int* __restrict__ fill, int* __restrict__ csr_src,
                               const int* __restrict__ flags, int e) {
    int i = blockIdx.x * blockDim.x + threadIdx.x;
    if (i < e) {
        int s = flags[0] ? src[2 * i] : src[i];
        int pos = atomicAdd(&fill[dst[i]], 1);
        csr_src[pos] = s;
    }
}

// ---------- S[n] = sum over incoming edges of hv[src] ----------
__global__ void gather_kernel(const int* __restrict__ row, const int* __restrict__ csr_src,
                              const float* __restrict__ hv, float* __restrict__ S) {
    int n = blockIdx.x;
    int j = threadIdx.x;
    int beg = row[n], end = row[n + 1];
    float s = 0.f;
    for (int e = beg; e < end; e++) {
        int src = csr_src[e];
        s += hv[(size_t)src * HH + j];
    }
    S[(size_t)n * HH + j] = s;
}

// ---------- 64x64-tile GEMM: C[m, nc] = epi( sum_k A[m,k] * W[nc, woff+k] ) ----------
// A fp32 row-major (lda); W fp32 row-major (ldw), rows are output cols.
// mode 0: outf = acc                          (a = S @ Wr^T)
// mode 1: outf += deg[m] * (acc + bias[nc])   (a += deg*(hv @ Wl^T + b))
// mode 2: outb = bf16(acc + bias[nc])         (gi / gh)
__global__ __launch_bounds__(256) void gemm_kernel(
    const float* __restrict__ A, int lda, int K,
    const float* __restrict__ W, int ldw, int woff,
    const float* __restrict__ bias, const int* __restrict__ deg,
    float* __restrict__ outf, __hip_bfloat16* __restrict__ outb,
    int ldc, int M, int mode) {
    __shared__ float As[16][68];
    __shared__ float Ws[16][68];
    int tid = threadIdx.x;
    int m0 = blockIdx.x * 64;
    int nc0 = blockIdx.y * 64;
    float acc[4][4] = {};
    int lr = tid >> 2;          // 0..63
    int lc = (tid & 3) << 2;    // 0,4,8,12
    int tx = tid & 15, ty = tid >> 4;

    for (int k0 = 0; k0 < K; k0 += 16) {
        float4 av = make_float4(0.f, 0.f, 0.f, 0.f);
        int m = m0 + lr;
        if (m < M) av = *(const float4*)(A + (size_t)m * lda + k0 + lc);
        As[lc + 0][lr] = av.x; As[lc + 1][lr] = av.y;
        As[lc + 2][lr] = av.z; As[lc + 3][lr] = av.w;
        float4 wv = *(const float4*)(W + (size_t)(nc0 + lr) * ldw + woff + k0 + lc);
        Ws[lc + 0][lr] = wv.x; Ws[lc + 1][lr] = wv.y;
        Ws[lc + 2][lr] = wv.z; Ws[lc + 3][lr] = wv.w;
        __syncthreads();
        #pragma unroll
        for (int k = 0; k < 16; k++) {
            float a4[4], w4[4];
            *(float4*)a4 = *(const float4*)&As[k][ty * 4];
            *(float4*)w4 = *(const float4*)&Ws[k][tx * 4];
            #pragma unroll
            for (int i = 0; i < 4; i++)
                #pragma unroll
                for (int j = 0; j < 4; j++)
                    acc[i][j] += a4[i] * w4[j];
        }
        __syncthreads();
    }

    #pragma unroll
    for (int i = 0; i < 4; i++) {
        int m = m0 + ty * 4 + i;
        if (m >= M) continue;
        #pragma unroll
        for (int j = 0; j < 4; j++) {
            int nc = nc0 + tx * 4 + j;
            float v = acc[i][j];
            size_t o = (size_t)m * ldc + nc;
            if (mode == 0) {
                outf[o] = v;
            } else if (mode == 1) {
                float d = (float)deg[m];
                outf[o] += d * (v + bias[nc]);
            } else {
                outb[o] = __float2bfloat16(v + bias[nc]);
            }
        }
    }
}

// ---------- fused GRU gates, hv updated in place; dtype-aware output ----------
__global__ void gate_kernel(const __hip_bfloat16* __restrict__ gi,
                            const __hip_bfloat16* __restrict__ gh,
                            float* __restrict__ hv, void* __restrict__ outv,
                            const int* __restrict__ flags, int writeOut, int total) {
    int idx = blockIdx.x * blockDim.x + threadIdx.x;
    if (idx >= total) return;
    int n = idx >> 7;
    int j = idx & 127;
    size_t base = (size_t)n * 384;
    float i_r = __bfloat162float(gi[base + j]);
    float i_z = __bfloat162float(gi[base + 128 + j]);
    float i_n = __bfloat162float(gi[base + 256 + j]);
    float h_r = __bfloat162float(gh[base + j]);
    float h_z = __bfloat162float(gh[base + 128 + j]);
    float h_n = __bfloat162float(gh[base + 256 + j]);
    float h = hv[idx];
    float r = 1.f / (1.f + __expf(-(i_r + h_r)));
    float z = 1.f / (1.f + __expf(-(i_z + h_z)));
    float nn = tanhf(i_n + r * h_n);
    float hn = (1.f - z) * nn + z * h;
    hv[idx] = hn;
    if (writeOut) {
        if (flags[1]) ((float*)outv)[idx] = hn;
        else ((__hip_bfloat16*)outv)[idx] = __float2bfloat16(hn);
    }
}

extern "C" void kernel_launch(void* const* d_in, const int* in_sizes, int n_in,
                              void* d_out, int out_size, void* d_ws, size_t ws_size,
                              hipStream_t stream) {
    const void* hv_in  = d_in[0];
    const int* edge_src = (const int*)d_in[1];
    const int* edge_dst = (const int*)d_in[2];
    const void* msg_W = d_in[3];
    const void* msg_b = d_in[4];
    const void* gWih  = d_in[5];
    const void* gWhh  = d_in[6];
    const void* gbih  = d_in[7];
    const void* gbhh  = d_in[8];

    // ---- workspace carve-up (~124 MB), control buffers first ----
    char* p = (char*)d_ws;
    auto alloc = [&](size_t bytes) -> void* {
        void* r = (void*)p;
        p += (bytes + 255) & ~(size_t)255;
        return r;
    };
    int* flags   = (int*)alloc(256);
    int* deg     = (int*)alloc((size_t)NN * 4);
    int* row     = (int*)alloc((size_t)(NN + 1) * 4);
    int* fill    = (int*)alloc((size_t)NN * 4);
    int* csr_src = (int*)alloc((size_t)NE * 4);                 // 6.4 MB
    float* wMsg  = (float*)alloc((size_t)TT * 256 * 256 * 4);   // 0.52 MB
    float* wIh   = (float*)alloc((size_t)TT * 384 * 256 * 4);   // 0.79 MB
    float* wHh   = (float*)alloc((size_t)TT * 384 * 128 * 4);   // 0.39 MB
    float* bMsg  = (float*)alloc((size_t)TT * 256 * 4);
    float* bIh   = (float*)alloc((size_t)TT * 384 * 4);
    float* bHh   = (float*)alloc((size_t)TT * 384 * 4);
    float* hv32  = (float*)alloc((size_t)NN * HH * 4);          // 25.6 MB
    char*  R1    = (char*)alloc((size_t)NN * 384 * 2);          // 38.4 MB: S f32 -> gi bf16
    char*  R2    = (char*)alloc((size_t)NN * 256 * 4);          // 51.2 MB: a f32 -> gh bf16
    (void)ws_size; (void)in_sizes; (void)n_in; (void)out_size;

    float* S = (float*)R1;
    __hip_bfloat16* gi = (__hip_bfloat16*)R1;
    float* a = (float*)R2;
    __hip_bfloat16* gh = (__hip_bfloat16*)R2;

    // ---- dtype detection ----
    detect_kernel<<<1, 64, 0, stream>>>((const unsigned short*)hv_in, edge_src, flags);

    hipMemsetAsync(deg, 0, (size_t)NN * 4, stream);

    // ---- float inputs -> fp32 workspace copies ----
    auto conv = [&](const void* src, float* dst, int n) {
        conv_kernel<<<(n + 255) / 256, 256, 0, stream>>>(src, dst, n, flags);
    };
    conv(hv_in, hv32, NN * HH);
    conv(msg_W, wMsg, TT * 256 * 256);
    conv(msg_b, bMsg, TT * 256);
    conv(gWih, wIh, TT * 384 * 256);
    conv(gWhh, wHh, TT * 384 * 128);
    conv(gbih, bIh, TT * 384);
    conv(gbhh, bHh, TT * 384);

    // ---- CSR build (counting sort by dst) ----
    hist_kernel<<<(NE + 255) / 256, 256, 0, stream>>>(edge_dst, deg, NE);
    scan_kernel<<<1, 1024, 0, stream>>>(deg, row, fill, NN);
    scatter_kernel<<<(NE + 255) / 256, 256, 0, stream>>>(edge_src, edge_dst, fill, csr_src, flags, NE);

    dim3 blk(256);
    int mt = (NN + 63) / 64;  // 782 row tiles

    for (int t = 0; t < TT; t++) {
        // S[n] = sum of hv[src] over incoming edges (writes R1)
        gather_kernel<<<NN, HH, 0, stream>>>(row, csr_src, hv32, S);

        // a = S @ Wr^T   (Wr = msg_W[t][:, 128:256])  (R1 -> R2)
        gemm_kernel<<<dim3(mt, 4), blk, 0, stream>>>(
            S, HH, HH, wMsg + (size_t)t * 256 * 256, 256, 128,
            nullptr, nullptr, a, nullptr, 256, NN, 0);
        // a += deg * (hv @ Wl^T + b)
        gemm_kernel<<<dim3(mt, 4), blk, 0, stream>>>(
            hv32, HH, HH, wMsg + (size_t)t * 256 * 256, 256, 0,
            bMsg + (size_t)t * 256, deg, a, nullptr, 256, NN, 1);
        // gi = bf16(a @ Wih^T + bih)   (R2 -> R1, S dead)
        gemm_kernel<<<dim3(mt, 6), blk, 0, stream>>>(
            a, 256, 256, wIh + (size_t)t * 384 * 256, 256, 0,
            bIh + (size_t)t * 384, nullptr, nullptr, gi, 384, NN, 2);
        // gh = bf16(hv @ Whh^T + bhh)  (-> R2, a dead)
        gemm_kernel<<<dim3(mt, 6), blk, 0, stream>>>(
            hv32, HH, HH, wHh + (size_t)t * 384 * 128, 128, 0,
            bHh + (size_t)t * 384, nullptr, nullptr, gh, 384, NN, 2);
        // GRU gates, hv in place; dtype-aware output on last round
        gate_kernel<<<(NN * HH + 255) / 256, 256, 0, stream>>>(
            gi, gh, hv32, d_out, flags, (t == TT - 1) ? 1 : 0, NN * HH);
    }
}

// Round 5
// 1035.360 us; speedup vs baseline: 1.3967x; 1.3967x over previous
//
#include <hip/hip_runtime.h>
#include <hip/hip_bf16.h>

// GraphProp via linearity trick:
//   a[n] = Wl@(deg[n]*h[n]) + Wr@S[n] + deg[n]*b,  S[n] = sum_{e:dst=n} h[src]
// R5: split-precision f16 MFMA GEMMs (A fp32 split hi/lo in staging, W pre-split;
// acc += Ah*Wh + Al*Wh + Ah*Wl -> ~fp32-accurate products at MFMA speed).
// R4 post-mortem: direct-f16 operands stacked 3 rounding terms -> absmax 0.123.
// State fp32; gi/gh f16 (saturation-safe); ws carve 124.1 MB (= R3's proven size).

#define NN 50000
#define NE 1600000
#define HH 128
#define TT 2

typedef _Float16 half8 __attribute__((ext_vector_type(8)));
typedef float floatx4 __attribute__((ext_vector_type(4)));

__device__ __forceinline__ float bf2f(unsigned short u) {
    union { unsigned int i; float f; } c;
    c.i = ((unsigned int)u) << 16;
    return c.f;
}

// ---------- dtype detectors: flags[0]=src int64, flags[1]=floats are fp32 ----------
__global__ void detect_kernel(const unsigned short* __restrict__ hv_u16,
                              const int* __restrict__ src, int* __restrict__ flags) {
    int i = threadIdx.x;  // 64 threads
    int garbage = 0;
    for (int k = 0; k < 4; k++) {
        unsigned short u = hv_u16[2 * (i * 4 + k)];
        int e = (u >> 7) & 0xFF;
        if (e >= 0x90 || (e <= 0x60 && (u & 0x7FFF) != 0)) garbage++;
    }
    unsigned long long gb = __ballot(garbage > 0);
    int odd = src[2 * i + 1];
    unsigned long long bal = __ballot(odd == 0);
    if (i == 0) {
        flags[1] = (__popcll(gb) >= 8) ? 1 : 0;
        flags[0] = (bal == 0xFFFFFFFFFFFFFFFFull) ? 1 : 0;
    }
}

// ---------- flag-aware converts ----------
__global__ void conv_f32_kernel(const void* __restrict__ in, float* __restrict__ out,
                                int n, const int* __restrict__ flags) {
    int i = blockIdx.x * blockDim.x + threadIdx.x;
    if (i >= n) return;
    out[i] = flags[1] ? ((const float*)in)[i] : bf2f(((const unsigned short*)in)[i]);
}
// weight split: wh = f16(v), wl = f16(v - wh)
__global__ void wsplit_kernel(const void* __restrict__ in, _Float16* __restrict__ wh,
                              _Float16* __restrict__ wl, int n, const int* __restrict__ flags) {
    int i = blockIdx.x * blockDim.x + threadIdx.x;
    if (i >= n) return;
    float v = flags[1] ? ((const float*)in)[i] : bf2f(((const unsigned short*)in)[i]);
    _Float16 h = (_Float16)v;
    wh[i] = h;
    wl[i] = (_Float16)(v - (float)h);
}

// ---------- CSR build ----------
__global__ void hist_kernel(const int* __restrict__ dst, int* __restrict__ deg, int e) {
    int i = blockIdx.x * blockDim.x + threadIdx.x;
    if (i < e) atomicAdd(&deg[dst[i]], 1);
}

__global__ void scan_kernel(const int* __restrict__ deg, int* __restrict__ row,
                            int* __restrict__ fill, int n) {
    __shared__ int sh[1024];
    __shared__ int s_running;
    if (threadIdx.x == 0) s_running = 0;
    __syncthreads();
    int nch = (n + 1024) / 1024;
    for (int c = 0; c < nch; c++) {
        int idx = c * 1024 + threadIdx.x;
        int v = (idx < n) ? deg[idx] : 0;
        sh[threadIdx.x] = v;
        __syncthreads();
        for (int off = 1; off < 1024; off <<= 1) {
            int t = (threadIdx.x >= off) ? sh[threadIdx.x - off] : 0;
            __syncthreads();
            sh[threadIdx.x] += t;
            __syncthreads();
        }
        int incl = sh[threadIdx.x];
        int excl = incl - v;
        int base = s_running;
        if (idx <= n) row[idx] = base + excl;
        if (idx < n) fill[idx] = base + excl;
        __syncthreads();
        if (threadIdx.x == 1023) s_running = base + incl;
        __syncthreads();
    }
}

__global__ void scatter_kernel(const int* __restrict__ src, const int* __restrict__ dst,
                               int* __restrict__ fill, int* __restrict__ csr_src,
                               const int* __restrict__ flags, int e) {
    int i = blockIdx.x * blockDim.x + threadIdx.x;
    if (i < e) {
        int s = flags[0] ? src[2 * i] : src[i];
        int pos = atomicAdd(&fill[dst[i]], 1);
        csr_src[pos] = s;
    }
}

// ---------- S[n] = sum over incoming edges of hv[src] (fp32, R3-proven) ----------
__global__ void gather_kernel(const int* __restrict__ row, const int* __restrict__ csr_src,
                              const float* __restrict__ hv, float* __restrict__ S) {
    int n = blockIdx.x;
    int j = threadIdx.x;
    int beg = row[n], end = row[n + 1];
    float s = 0.f;
    for (int e = beg; e < end; e++) {
        int src = csr_src[e];
        s += hv[(size_t)src * HH + j];
    }
    S[(size_t)n * HH + j] = s;
}

// ---------- split-precision MFMA GEMM ----------
// C[m,n] = epi( sum_k Avirt[m,k] * W[n,k] ), fp32-accurate via f16 hi/lo split:
//   acc += Ah*Wh + Al*Wh + Ah*Wl   (Al*Wl ~2^-22, dropped)
// Avirt: cols [0,Kleft) from Aleft (row stride Kleft; scaled by deg[m] iff mode 0),
//        cols [Kleft,K) from Aright (row stride K-Kleft). A fp32, split in staging.
// W pre-split f16 (Wh/Wl, [Nout x K] row-major).
// mode 0: outf[m*ldc+n] = acc + deg[m]*bias[n]   (a-GEMM, fp32 out)
// mode 1: outh[m*ldc+n] = f16(acc + bias[n])     (gi / gh)
__global__ __launch_bounds__(256) void mfma_gemm_kernel(
    const float* __restrict__ Aleft, const float* __restrict__ Aright, int Kleft, int K,
    const _Float16* __restrict__ Wh, const _Float16* __restrict__ Wl,
    const float* __restrict__ bias, const int* __restrict__ deg,
    float* __restrict__ outf, _Float16* __restrict__ outh,
    int ldc, int M, int mode) {
    __shared__ _Float16 Ash[128][40];  // +8 pad
    __shared__ _Float16 Asl[128][40];
    __shared__ _Float16 Wsh[128][40];
    __shared__ _Float16 Wsl[128][40];
    int tid = threadIdx.x;
    int m0 = blockIdx.x * 128, n0 = blockIdx.y * 128;
    int wave = tid >> 6, lane = tid & 63;
    int wm = (wave & 1) * 64, wn = (wave >> 1) * 64;
    int lr = lane & 15, quad = lane >> 4;
    floatx4 acc[4][4] = {};
    int r0 = tid >> 2, c0 = (tid & 3) * 8;  // staging rows r0, r0+64; 8-elem chunk c0

    float ds0 = 1.f, ds1 = 1.f;  // deg scale for left half (mode 0)
    if (mode == 0) {
        if (m0 + r0 < M) ds0 = (float)deg[m0 + r0];
        if (m0 + r0 + 64 < M) ds1 = (float)deg[m0 + r0 + 64];
    }

    for (int k0 = 0; k0 < K; k0 += 32) {
        bool left = (k0 < Kleft);  // Kleft % 32 == 0 -> uniform per iteration
        const float* Asrc = left ? Aleft : Aright;
        int astr = left ? Kleft : (K - Kleft);
        int kk = (left ? k0 : k0 - Kleft) + c0;
        float f0[8] = {}, f1[8] = {};
        int gm0 = m0 + r0, gm1 = m0 + r0 + 64;
        if (gm0 < M) {
            *(float4*)&f0[0] = *(const float4*)(Asrc + (size_t)gm0 * astr + kk);
            *(float4*)&f0[4] = *(const float4*)(Asrc + (size_t)gm0 * astr + kk + 4);
        }
        if (gm1 < M) {
            *(float4*)&f1[0] = *(const float4*)(Asrc + (size_t)gm1 * astr + kk);
            *(float4*)&f1[4] = *(const float4*)(Asrc + (size_t)gm1 * astr + kk + 4);
        }
        if (left && mode == 0) {
            #pragma unroll
            for (int q = 0; q < 8; q++) { f0[q] *= ds0; f1[q] *= ds1; }
        }
        half8 wh0 = *(const half8*)(Wh + (size_t)(n0 + r0) * K + k0 + c0);
        half8 wh1 = *(const half8*)(Wh + (size_t)(n0 + r0 + 64) * K + k0 + c0);
        half8 wl0 = *(const half8*)(Wl + (size_t)(n0 + r0) * K + k0 + c0);
        half8 wl1 = *(const half8*)(Wl + (size_t)(n0 + r0 + 64) * K + k0 + c0);
        __syncthreads();  // previous iteration's frag reads done
        #pragma unroll
        for (int q = 0; q < 8; q++) {
            _Float16 h0 = (_Float16)f0[q], h1 = (_Float16)f1[q];
            Ash[r0][c0 + q] = h0;        Asl[r0][c0 + q] = (_Float16)(f0[q] - (float)h0);
            Ash[r0 + 64][c0 + q] = h1;   Asl[r0 + 64][c0 + q] = (_Float16)(f1[q] - (float)h1);
        }
        *(half8*)&Wsh[r0][c0] = wh0;
        *(half8*)&Wsh[r0 + 64][c0] = wh1;
        *(half8*)&Wsl[r0][c0] = wl0;
        *(half8*)&Wsl[r0 + 64][c0] = wl1;
        __syncthreads();
        half8 afh[4], afl[4], bfh[4], bfl[4];
        #pragma unroll
        for (int mt = 0; mt < 4; mt++) {
            afh[mt] = *(const half8*)&Ash[wm + mt * 16 + lr][quad * 8];
            afl[mt] = *(const half8*)&Asl[wm + mt * 16 + lr][quad * 8];
        }
        #pragma unroll
        for (int nt = 0; nt < 4; nt++) {
            bfh[nt] = *(const half8*)&Wsh[wn + nt * 16 + lr][quad * 8];
            bfl[nt] = *(const half8*)&Wsl[wn + nt * 16 + lr][quad * 8];
        }
        #pragma unroll
        for (int mt = 0; mt < 4; mt++)
            #pragma unroll
            for (int nt = 0; nt < 4; nt++) {
                acc[mt][nt] = __builtin_amdgcn_mfma_f32_16x16x32_f16(afh[mt], bfh[nt], acc[mt][nt], 0, 0, 0);
                acc[mt][nt] = __builtin_amdgcn_mfma_f32_16x16x32_f16(afl[mt], bfh[nt], acc[mt][nt], 0, 0, 0);
                acc[mt][nt] = __builtin_amdgcn_mfma_f32_16x16x32_f16(afh[mt], bfl[nt], acc[mt][nt], 0, 0, 0);
            }
    }

    // D layout: col = lane&15, row = quad*4 + reg  [m89/m91 verified; R4 confirmed]
    #pragma unroll
    for (int mt = 0; mt < 4; mt++) {
        #pragma unroll
        for (int r = 0; r < 4; r++) {
            int m = m0 + wm + mt * 16 + quad * 4 + r;
            if (m >= M) continue;
            #pragma unroll
            for (int nt = 0; nt < 4; nt++) {
                int n = n0 + wn + nt * 16 + lr;
                float v = acc[mt][nt][r];
                size_t o = (size_t)m * ldc + n;
                if (mode == 0) outf[o] = v + (float)deg[m] * bias[n];
                else outh[o] = (_Float16)(v + bias[n]);
            }
        }
    }
}

// ---------- fused GRU gates, fp32 state in place; dtype-aware final output ----------
__global__ void gate_kernel(const _Float16* __restrict__ gi,
                            const _Float16* __restrict__ gh,
                            float* __restrict__ hv, void* __restrict__ outv,
                            const int* __restrict__ flags, int writeOut, int total) {
    int idx = blockIdx.x * blockDim.x + threadIdx.x;
    if (idx >= total) return;
    int n = idx >> 7;
    int j = idx & 127;
    size_t base = (size_t)n * 384;
    float i_r = (float)gi[base + j];
    float i_z = (float)gi[base + 128 + j];
    float i_n = (float)gi[base + 256 + j];
    float h_r = (float)gh[base + j];
    float h_z = (float)gh[base + 128 + j];
    float h_n = (float)gh[base + 256 + j];
    float h = hv[idx];
    float r = 1.f / (1.f + __expf(-(i_r + h_r)));
    float z = 1.f / (1.f + __expf(-(i_z + h_z)));
    float nn = tanhf(i_n + r * h_n);
    float hn = (1.f - z) * nn + z * h;
    hv[idx] = hn;
    if (writeOut) {
        if (flags[1]) ((float*)outv)[idx] = hn;
        else ((__hip_bfloat16*)outv)[idx] = __float2bfloat16(hn);
    }
}

extern "C" void kernel_launch(void* const* d_in, const int* in_sizes, int n_in,
                              void* d_out, int out_size, void* d_ws, size_t ws_size,
                              hipStream_t stream) {
    const void* hv_in   = d_in[0];
    const int* edge_src = (const int*)d_in[1];
    const int* edge_dst = (const int*)d_in[2];
    const void* msg_W = d_in[3];
    const void* msg_b = d_in[4];
    const void* gWih  = d_in[5];
    const void* gWhh  = d_in[6];
    const void* gbih  = d_in[7];
    const void* gbhh  = d_in[8];

    // ---- workspace carve-up (~124.1 MB, = R3's proven footprint) ----
    char* p = (char*)d_ws;
    auto alloc = [&](size_t bytes) -> void* {
        void* r = (void*)p;
        p += (bytes + 255) & ~(size_t)255;
        return r;
    };
    int* flags   = (int*)alloc(256);
    int* deg     = (int*)alloc((size_t)NN * 4);
    int* row     = (int*)alloc((size_t)(NN + 1) * 4);
    int* fill    = (int*)alloc((size_t)NN * 4);
    int* csr_src = (int*)alloc((size_t)NE * 4);                       // 6.4 MB
    _Float16* wMsgH = (_Float16*)alloc((size_t)TT * 256 * 256 * 2);
    _Float16* wMsgL = (_Float16*)alloc((size_t)TT * 256 * 256 * 2);
    _Float16* wIhH  = (_Float16*)alloc((size_t)TT * 384 * 256 * 2);
    _Float16* wIhL  = (_Float16*)alloc((size_t)TT * 384 * 256 * 2);
    _Float16* wHhH  = (_Float16*)alloc((size_t)TT * 384 * 128 * 2);
    _Float16* wHhL  = (_Float16*)alloc((size_t)TT * 384 * 128 * 2);
    float* bMsg  = (float*)alloc((size_t)TT * 256 * 4);
    float* bIh   = (float*)alloc((size_t)TT * 384 * 4);
    float* bHh   = (float*)alloc((size_t)TT * 384 * 4);
    float* hv32  = (float*)alloc((size_t)NN * HH * 4);                // 25.6 MB
    char* P1 = (char*)alloc((size_t)NN * 256 * 4);                    // 51.2 MB: a f32 -> gh f16
    char* P2 = (char*)alloc((size_t)NN * 384 * 2);                    // 38.4 MB: S f32 -> gi f16
    (void)ws_size; (void)in_sizes; (void)n_in; (void)out_size;

    float* a32 = (float*)P1;
    _Float16* gh = (_Float16*)P1;
    float* S = (float*)P2;      // 25.6 MB of P2
    _Float16* gi = (_Float16*)P2;

    // ---- dtype detection + conversions ----
    detect_kernel<<<1, 64, 0, stream>>>((const unsigned short*)hv_in, edge_src, flags);
    hipMemsetAsync(deg, 0, (size_t)NN * 4, stream);

    auto wsplit = [&](const void* src, _Float16* wh, _Float16* wl, int n) {
        wsplit_kernel<<<(n + 255) / 256, 256, 0, stream>>>(src, wh, wl, n, flags);
    };
    auto c32 = [&](const void* src, float* dst, int n) {
        conv_f32_kernel<<<(n + 255) / 256, 256, 0, stream>>>(src, dst, n, flags);
    };
    c32(hv_in, hv32, NN * HH);
    wsplit(msg_W, wMsgH, wMsgL, TT * 256 * 256);
    wsplit(gWih, wIhH, wIhL, TT * 384 * 256);
    wsplit(gWhh, wHhH, wHhL, TT * 384 * 128);
    c32(msg_b, bMsg, TT * 256);
    c32(gbih, bIh, TT * 384);
    c32(gbhh, bHh, TT * 384);

    // ---- CSR build ----
    hist_kernel<<<(NE + 255) / 256, 256, 0, stream>>>(edge_dst, deg, NE);
    scan_kernel<<<1, 1024, 0, stream>>>(deg, row, fill, NN);
    scatter_kernel<<<(NE + 255) / 256, 256, 0, stream>>>(edge_src, edge_dst, fill, csr_src, flags, NE);

    int mt128 = (NN + 127) / 128;  // 391

    for (int t = 0; t < TT; t++) {
        // S (fp32) into P2
        gather_kernel<<<NN, HH, 0, stream>>>(row, csr_src, hv32, S);
        // a = [deg*hv | S] @ msg_W^T + deg*b  (fp32 out -> P1)
        mfma_gemm_kernel<<<dim3(mt128, 2), 256, 0, stream>>>(
            hv32, S, 128, 256,
            wMsgH + (size_t)t * 256 * 256, wMsgL + (size_t)t * 256 * 256,
            bMsg + (size_t)t * 256, deg, a32, nullptr, 256, NN, 0);
        // gi = f16(a @ Wih^T + bih)  (-> P2, S dead)
        mfma_gemm_kernel<<<dim3(mt128, 3), 256, 0, stream>>>(
            a32, nullptr, 256, 256,
            wIhH + (size_t)t * 384 * 256, wIhL + (size_t)t * 384 * 256,
            bIh + (size_t)t * 384, deg, nullptr, gi, 384, NN, 1);
        // gh = f16(hv @ Whh^T + bhh)  (-> P1, a dead)
        mfma_gemm_kernel<<<dim3(mt128, 3), 256, 0, stream>>>(
            hv32, nullptr, 128, 128,
            wHhH + (size_t)t * 384 * 128, wHhL + (size_t)t * 384 * 128,
            bHh + (size_t)t * 384, deg, nullptr, gh, 384, NN, 1);
        // GRU gates, hv32 in place; dtype-aware output on last round
        gate_kernel<<<(NN * HH + 255) / 256, 256, 0, stream>>>(
            gi, gh, hv32, d_out, flags, (t == TT - 1) ? 1 : 0, NN * HH);
    }
}

// Round 6
// 888.508 us; speedup vs baseline: 1.6276x; 1.1653x over previous
//
#include <hip/hip_runtime.h>
#include <hip/hip_bf16.h>

// GraphProp via linearity trick:
//   a[n] = Wl@(deg[n]*h[n]) + Wr@S[n] + deg[n]*b,  S[n] = sum_{e:dst=n} h[src]
// R6: state/S/a as exact f16 hi/lo planes (split once by producers, GEMM staging
// is pure half8 copies; 3-term MFMA Ah*Wh+Al*Wh+Ah*Wl ~ fp32 accuracy).
// Gather reads hvH only (f16, half traffic; added err ~0.01 per analysis).
// Shuffle-based scan. ws carve ~125 MB (proven level).

#define NN 50000
#define NE 1600000
#define HH 128
#define TT 2

typedef _Float16 half8 __attribute__((ext_vector_type(8)));
typedef _Float16 half2v __attribute__((ext_vector_type(2)));
typedef float floatx4 __attribute__((ext_vector_type(4)));

__device__ __forceinline__ float bf2f(unsigned short u) {
    union { unsigned int i; float f; } c;
    c.i = ((unsigned int)u) << 16;
    return c.f;
}

// ---------- dtype detectors: flags[0]=src int64, flags[1]=floats are fp32 ----------
__global__ void detect_kernel(const unsigned short* __restrict__ hv_u16,
                              const int* __restrict__ src, int* __restrict__ flags) {
    int i = threadIdx.x;  // 64 threads
    int garbage = 0;
    for (int k = 0; k < 4; k++) {
        unsigned short u = hv_u16[2 * (i * 4 + k)];
        int e = (u >> 7) & 0xFF;
        if (e >= 0x90 || (e <= 0x60 && (u & 0x7FFF) != 0)) garbage++;
    }
    unsigned long long gb = __ballot(garbage > 0);
    int odd = src[2 * i + 1];
    unsigned long long bal = __ballot(odd == 0);
    if (i == 0) {
        flags[1] = (__popcll(gb) >= 8) ? 1 : 0;
        flags[0] = (bal == 0xFFFFFFFFFFFFFFFFull) ? 1 : 0;
    }
}

// ---------- flag-aware converts ----------
__global__ void conv_f32_kernel(const void* __restrict__ in, float* __restrict__ out,
                                int n, const int* __restrict__ flags) {
    int i = blockIdx.x * blockDim.x + threadIdx.x;
    if (i >= n) return;
    out[i] = flags[1] ? ((const float*)in)[i] : bf2f(((const unsigned short*)in)[i]);
}
// split: h = f16(v), l = f16(v - h)
__global__ void split_kernel(const void* __restrict__ in, _Float16* __restrict__ ph,
                             _Float16* __restrict__ pl, int n, const int* __restrict__ flags) {
    int i = blockIdx.x * blockDim.x + threadIdx.x;
    if (i >= n) return;
    float v = flags[1] ? ((const float*)in)[i] : bf2f(((const unsigned short*)in)[i]);
    _Float16 h = (_Float16)v;
    ph[i] = h;
    pl[i] = (_Float16)(v - (float)h);
}

// ---------- CSR build ----------
__global__ void hist_kernel(const int* __restrict__ dst, int* __restrict__ deg, int e) {
    int i = blockIdx.x * blockDim.x + threadIdx.x;
    if (i < e) atomicAdd(&deg[dst[i]], 1);
}

// shuffle-based single-block exclusive scan (1024 thr, 16 waves)
__global__ void scan_kernel(const int* __restrict__ deg, int* __restrict__ row,
                            int* __restrict__ fill, int n) {
    __shared__ int wsum[16];
    __shared__ int s_running;
    int tid = threadIdx.x, lane = tid & 63, w = tid >> 6;
    if (tid == 0) s_running = 0;
    __syncthreads();
    int nch = (n + 1024) / 1024;
    for (int c = 0; c < nch; c++) {
        int idx = c * 1024 + tid;
        int v = (idx < n) ? deg[idx] : 0;
        int s = v;
        #pragma unroll
        for (int off = 1; off < 64; off <<= 1) {
            int t = __shfl_up(s, off, 64);
            if (lane >= off) s += t;
        }
        if (lane == 63) wsum[w] = s;
        __syncthreads();
        if (w == 0) {
            int ws = (lane < 16) ? wsum[lane] : 0;
            #pragma unroll
            for (int off = 1; off < 16; off <<= 1) {
                int t = __shfl_up(ws, off, 64);
                if (lane >= off) ws += t;
            }
            if (lane < 16) wsum[lane] = ws;  // inclusive wave prefix
        }
        __syncthreads();
        int incl = s + ((w > 0) ? wsum[w - 1] : 0);
        int excl = incl - v;
        int base = s_running;
        if (idx < n) { row[idx] = base + excl; fill[idx] = base + excl; }
        else if (idx == n) row[idx] = base + excl;
        __syncthreads();
        if (tid == 1023) s_running = base + incl;
        __syncthreads();
    }
}

__global__ void scatter_kernel(const int* __restrict__ src, const int* __restrict__ dst,
                               int* __restrict__ fill, int* __restrict__ csr_src,
                               const int* __restrict__ flags, int e) {
    int i = blockIdx.x * blockDim.x + threadIdx.x;
    if (i < e) {
        int s = flags[0] ? src[2 * i] : src[i];
        int pos = atomicAdd(&fill[dst[i]], 1);
        csr_src[pos] = s;
    }
}

// ---------- S[n] = sum_{e} hvH[src] (f16 reads, fp32 accum, hi/lo split out) ----------
__global__ void gather_kernel(const int* __restrict__ row, const int* __restrict__ csr_src,
                              const _Float16* __restrict__ hvH,
                              _Float16* __restrict__ SH, _Float16* __restrict__ SL) {
    int n = blockIdx.x;
    int j = threadIdx.x;  // 64 threads, cols 2j, 2j+1
    const half2v* hv2 = (const half2v*)hvH;
    int beg = row[n], end = row[n + 1];
    float sx = 0.f, sy = 0.f;
    for (int e = beg; e < end; e++) {
        half2v v = hv2[(size_t)csr_src[e] * 64 + j];
        sx += (float)v.x; sy += (float)v.y;
    }
    half2v hx, lx;
    hx.x = (_Float16)sx; lx.x = (_Float16)(sx - (float)hx.x);
    hx.y = (_Float16)sy; lx.y = (_Float16)(sy - (float)hx.y);
    ((half2v*)SH)[(size_t)n * 64 + j] = hx;
    ((half2v*)SL)[(size_t)n * 64 + j] = lx;
}

// ---------- split-precision MFMA GEMM, all-f16-plane operands ----------
// C[m,n] = epi( sum_k Avirt[m,k] * W[n,k] );  acc += Ah*Wh + Al*Wh + Ah*Wl.
// Avirt cols [0,Kleft) from plane pair (AhA,AlA) stride Kleft — scaled by deg[m] iff mode 0;
//       cols [Kleft,K) from (AhB,AlB) stride K-Kleft. W pre-split [Nout x K].
// mode 0: v = acc + deg[m]*bias[n]; outH/outL = hi/lo(v)      (a-GEMM)
// mode 1: outH = f16(acc + bias[n])                            (gi / gh)
__global__ __launch_bounds__(256) void mfma_gemm_kernel(
    const _Float16* __restrict__ AhA, const _Float16* __restrict__ AlA,
    const _Float16* __restrict__ AhB, const _Float16* __restrict__ AlB,
    int Kleft, int K,
    const _Float16* __restrict__ Wh, const _Float16* __restrict__ Wl,
    const float* __restrict__ bias, const int* __restrict__ deg,
    _Float16* __restrict__ outH, _Float16* __restrict__ outL,
    int ldc, int M, int mode) {
    __shared__ _Float16 Ash[128][40];  // +8 pad
    __shared__ _Float16 Asl[128][40];
    __shared__ _Float16 Wsh[128][40];
    __shared__ _Float16 Wsl[128][40];
    int tid = threadIdx.x;
    int m0 = blockIdx.x * 128, n0 = blockIdx.y * 128;
    int wave = tid >> 6, lane = tid & 63;
    int wm = (wave & 1) * 64, wn = (wave >> 1) * 64;
    int lr = lane & 15, quad = lane >> 4;
    floatx4 acc[4][4] = {};
    int r0 = tid >> 2, c0 = (tid & 3) * 8;  // staging rows r0, r0+64; 8-f16 chunk c0

    float ds0 = 1.f, ds1 = 1.f;
    if (mode == 0) {
        if (m0 + r0 < M) ds0 = (float)deg[m0 + r0];
        if (m0 + r0 + 64 < M) ds1 = (float)deg[m0 + r0 + 64];
    }

    for (int k0 = 0; k0 < K; k0 += 32) {
        bool left = (k0 < Kleft);
        const _Float16* Ph = left ? AhA : AhB;
        const _Float16* Pl = left ? AlA : AlB;
        int astr = left ? Kleft : (K - Kleft);
        int kk = (left ? k0 : k0 - Kleft) + c0;
        int gm0 = m0 + r0, gm1 = m0 + r0 + 64;
        half8 ah0 = {}, al0 = {}, ah1 = {}, al1 = {};
        if (gm0 < M) {
            ah0 = *(const half8*)(Ph + (size_t)gm0 * astr + kk);
            al0 = *(const half8*)(Pl + (size_t)gm0 * astr + kk);
        }
        if (gm1 < M) {
            ah1 = *(const half8*)(Ph + (size_t)gm1 * astr + kk);
            al1 = *(const half8*)(Pl + (size_t)gm1 * astr + kk);
        }
        if (mode == 0 && left) {  // reconstruct, scale by deg, re-split
            #pragma unroll
            for (int q = 0; q < 8; q++) {
                float f0 = ((float)ah0[q] + (float)al0[q]) * ds0;
                float f1 = ((float)ah1[q] + (float)al1[q]) * ds1;
                _Float16 h0 = (_Float16)f0, h1 = (_Float16)f1;
                ah0[q] = h0; al0[q] = (_Float16)(f0 - (float)h0);
                ah1[q] = h1; al1[q] = (_Float16)(f1 - (float)h1);
            }
        }
        half8 wh0 = *(const half8*)(Wh + (size_t)(n0 + r0) * K + k0 + c0);
        half8 wh1 = *(const half8*)(Wh + (size_t)(n0 + r0 + 64) * K + k0 + c0);
        half8 wl0 = *(const half8*)(Wl + (size_t)(n0 + r0) * K + k0 + c0);
        half8 wl1 = *(const half8*)(Wl + (size_t)(n0 + r0 + 64) * K + k0 + c0);
        __syncthreads();  // previous iteration's frag reads done
        *(half8*)&Ash[r0][c0] = ah0;      *(half8*)&Ash[r0 + 64][c0] = ah1;
        *(half8*)&Asl[r0][c0] = al0;      *(half8*)&Asl[r0 + 64][c0] = al1;
        *(half8*)&Wsh[r0][c0] = wh0;      *(half8*)&Wsh[r0 + 64][c0] = wh1;
        *(half8*)&Wsl[r0][c0] = wl0;      *(half8*)&Wsl[r0 + 64][c0] = wl1;
        __syncthreads();
        half8 afh[4], afl[4], bfh[4], bfl[4];
        #pragma unroll
        for (int mt = 0; mt < 4; mt++) {
            afh[mt] = *(const half8*)&Ash[wm + mt * 16 + lr][quad * 8];
            afl[mt] = *(const half8*)&Asl[wm + mt * 16 + lr][quad * 8];
        }
        #pragma unroll
        for (int nt = 0; nt < 4; nt++) {
            bfh[nt] = *(const half8*)&Wsh[wn + nt * 16 + lr][quad * 8];
            bfl[nt] = *(const half8*)&Wsl[wn + nt * 16 + lr][quad * 8];
        }
        #pragma unroll
        for (int mt = 0; mt < 4; mt++)
            #pragma unroll
            for (int nt = 0; nt < 4; nt++) {
                acc[mt][nt] = __builtin_amdgcn_mfma_f32_16x16x32_f16(afh[mt], bfh[nt], acc[mt][nt], 0, 0, 0);
                acc[mt][nt] = __builtin_amdgcn_mfma_f32_16x16x32_f16(afl[mt], bfh[nt], acc[mt][nt], 0, 0, 0);
                acc[mt][nt] = __builtin_amdgcn_mfma_f32_16x16x32_f16(afh[mt], bfl[nt], acc[mt][nt], 0, 0, 0);
            }
    }

    // D layout: col = lane&15, row = quad*4 + reg  [m89/m91; R4/R5 confirmed]
    #pragma unroll
    for (int mt = 0; mt < 4; mt++) {
        #pragma unroll
        for (int r = 0; r < 4; r++) {
            int m = m0 + wm + mt * 16 + quad * 4 + r;
            if (m >= M) continue;
            #pragma unroll
            for (int nt = 0; nt < 4; nt++) {
                int n = n0 + wn + nt * 16 + lr;
                float v = acc[mt][nt][r];
                size_t o = (size_t)m * ldc + n;
                if (mode == 0) {
                    v += (float)deg[m] * bias[n];
                    _Float16 h = (_Float16)v;
                    outH[o] = h; outL[o] = (_Float16)(v - (float)h);
                } else {
                    outH[o] = (_Float16)(v + bias[n]);
                }
            }
        }
    }
}

// ---------- fused GRU gates; hi/lo state planes updated in place ----------
__global__ void gate_kernel(const _Float16* __restrict__ gi,
                            const _Float16* __restrict__ gh,
                            _Float16* __restrict__ hvH, _Float16* __restrict__ hvL,
                            void* __restrict__ outv,
                            const int* __restrict__ flags, int writeOut, int total) {
    int idx = blockIdx.x * blockDim.x + threadIdx.x;
    if (idx >= total) return;
    int n = idx >> 7;
    int j = idx & 127;
    size_t base = (size_t)n * 384;
    float i_r = (float)gi[base + j];
    float i_z = (float)gi[base + 128 + j];
    float i_n = (float)gi[base + 256 + j];
    float h_r = (float)gh[base + j];
    float h_z = (float)gh[base + 128 + j];
    float h_n = (float)gh[base + 256 + j];
    float h = (float)hvH[idx] + (float)hvL[idx];
    float r = 1.f / (1.f + __expf(-(i_r + h_r)));
    float z = 1.f / (1.f + __expf(-(i_z + h_z)));
    float nn = tanhf(i_n + r * h_n);
    float hn = (1.f - z) * nn + z * h;
    _Float16 hh = (_Float16)hn;
    hvH[idx] = hh;
    hvL[idx] = (_Float16)(hn - (float)hh);
    if (writeOut) {
        if (flags[1]) ((float*)outv)[idx] = hn;
        else ((__hip_bfloat16*)outv)[idx] = __float2bfloat16(hn);
    }
}

extern "C" void kernel_launch(void* const* d_in, const int* in_sizes, int n_in,
                              void* d_out, int out_size, void* d_ws, size_t ws_size,
                              hipStream_t stream) {
    const void* hv_in   = d_in[0];
    const int* edge_src = (const int*)d_in[1];
    const int* edge_dst = (const int*)d_in[2];
    const void* msg_W = d_in[3];
    const void* msg_b = d_in[4];
    const void* gWih  = d_in[5];
    const void* gWhh  = d_in[6];
    const void* gbih  = d_in[7];
    const void* gbhh  = d_in[8];

    // ---- workspace carve-up (~125 MB) ----
    char* p = (char*)d_ws;
    auto alloc = [&](size_t bytes) -> void* {
        void* r = (void*)p;
        p += (bytes + 255) & ~(size_t)255;
        return r;
    };
    int* flags   = (int*)alloc(256);
    int* deg     = (int*)alloc((size_t)NN * 4);
    int* row     = (int*)alloc((size_t)(NN + 1) * 4);
    int* fill    = (int*)alloc((size_t)NN * 4);
    int* csr_src = (int*)alloc((size_t)NE * 4);                       // 6.4 MB
    _Float16* wMsgH = (_Float16*)alloc((size_t)TT * 256 * 256 * 2);
    _Float16* wMsgL = (_Float16*)alloc((size_t)TT * 256 * 256 * 2);
    _Float16* wIhH  = (_Float16*)alloc((size_t)TT * 384 * 256 * 2);
    _Float16* wIhL  = (_Float16*)alloc((size_t)TT * 384 * 256 * 2);
    _Float16* wHhH  = (_Float16*)alloc((size_t)TT * 384 * 128 * 2);
    _Float16* wHhL  = (_Float16*)alloc((size_t)TT * 384 * 128 * 2);
    float* bMsg  = (float*)alloc((size_t)TT * 256 * 4);
    float* bIh   = (float*)alloc((size_t)TT * 384 * 4);
    float* bHh   = (float*)alloc((size_t)TT * 384 * 4);
    _Float16* hvH = (_Float16*)alloc((size_t)NN * HH * 2);            // 12.8 MB
    _Float16* hvL = (_Float16*)alloc((size_t)NN * HH * 2);            // 12.8 MB
    char* PA = (char*)alloc((size_t)NN * 256 * 2 * 2);                // 51.2 MB: aH+aL -> gh
    char* PB = (char*)alloc((size_t)NN * 384 * 2);                    // 38.4 MB: SH+SL -> gi
    (void)ws_size; (void)in_sizes; (void)n_in; (void)out_size;

    _Float16* aH = (_Float16*)PA;
    _Float16* aL = (_Float16*)(PA + (size_t)NN * 256 * 2);
    _Float16* gh = (_Float16*)PA;
    _Float16* SH = (_Float16*)PB;
    _Float16* SL = (_Float16*)(PB + (size_t)NN * HH * 2);
    _Float16* gi = (_Float16*)PB;

    // ---- dtype detection + conversions ----
    detect_kernel<<<1, 64, 0, stream>>>((const unsigned short*)hv_in, edge_src, flags);
    hipMemsetAsync(deg, 0, (size_t)NN * 4, stream);

    auto split = [&](const void* src, _Float16* ph, _Float16* pl, int n) {
        split_kernel<<<(n + 255) / 256, 256, 0, stream>>>(src, ph, pl, n, flags);
    };
    auto c32 = [&](const void* src, float* dst, int n) {
        conv_f32_kernel<<<(n + 255) / 256, 256, 0, stream>>>(src, dst, n, flags);
    };
    split(hv_in, hvH, hvL, NN * HH);
    split(msg_W, wMsgH, wMsgL, TT * 256 * 256);
    split(gWih, wIhH, wIhL, TT * 384 * 256);
    split(gWhh, wHhH, wHhL, TT * 384 * 128);
    c32(msg_b, bMsg, TT * 256);
    c32(gbih, bIh, TT * 384);
    c32(gbhh, bHh, TT * 384);

    // ---- CSR build ----
    hist_kernel<<<(NE + 255) / 256, 256, 0, stream>>>(edge_dst, deg, NE);
    scan_kernel<<<1, 1024, 0, stream>>>(deg, row, fill, NN);
    scatter_kernel<<<(NE + 255) / 256, 256, 0, stream>>>(edge_src, edge_dst, fill, csr_src, flags, NE);

    int mt128 = (NN + 127) / 128;  // 391

    for (int t = 0; t < TT; t++) {
        // S planes from hvH gather
        gather_kernel<<<NN, 64, 0, stream>>>(row, csr_src, hvH, SH, SL);
        // a = [deg*hv | S] @ msg_W^T + deg*b  -> aH/aL (PA)
        mfma_gemm_kernel<<<dim3(mt128, 2), 256, 0, stream>>>(
            hvH, hvL, SH, SL, 128, 256,
            wMsgH + (size_t)t * 256 * 256, wMsgL + (size_t)t * 256 * 256,
            bMsg + (size_t)t * 256, deg, aH, aL, 256, NN, 0);
        // gi = f16(a @ Wih^T + bih) -> PB (S dead)
        mfma_gemm_kernel<<<dim3(mt128, 3), 256, 0, stream>>>(
            aH, aL, aH, aL, 256, 256,
            wIhH + (size_t)t * 384 * 256, wIhL + (size_t)t * 384 * 256,
            bIh + (size_t)t * 384, deg, gi, nullptr, 384, NN, 1);
        // gh = f16(hv @ Whh^T + bhh) -> PA (a dead)
        mfma_gemm_kernel<<<dim3(mt128, 3), 256, 0, stream>>>(
            hvH, hvL, hvH, hvL, 128, 128,
            wHhH + (size_t)t * 384 * 128, wHhL + (size_t)t * 384 * 128,
            bHh + (size_t)t * 384, deg, gh, nullptr, 384, NN, 1);
        // GRU gates; hi/lo state planes in place; dtype-aware output on last round
        gate_kernel<<<(NN * HH + 255) / 256, 256, 0, stream>>>(
            gi, gh, hvH, hvL, d_out, flags, (t == TT - 1) ? 1 : 0, NN * HH);
    }
}